// Round 3
// baseline (142.535 us; speedup 1.0000x reference)
//
#include <hip/hip_runtime.h>

// CharGRU2: 2-layer GRU (reset_after=true) + dense + softmax, fp32.
// B=2048, T=128, V=256, H=20, L=15.
//
// Round 15 = R14 resubmit (previous bench died on container infra, not the
// kernel). LDS h-broadcast replaced by readlane->SGPR broadcast:
//
//  1. NO LDS. h0/h1 live in the 20 home lanes; after each h-update, 20
//     v_readlane_b32 (home lanes are compile-time constants) lift the state
//     into SGPRs. The recurrent dots are v_fmac_f32 with SGPR multiplier
//     (uniform h) x VGPR weight column — no ds_write/ds_read (~120cy+
//     lgkmcnt drain) anywhere in the recurrence cycle, no float4->v2f
//     extraction, no horizontal reductions (scalar fmac accumulates the
//     full dot directly).
//  2. SGPR live-range discipline: s1h readlanes are interleaved with the
//     rec1 fmac chain (produced-then-consumed) so ~20 h1 SGPRs don't stay
//     live across the backedge; only s0 (feeding two dot chains) is held.
//  3. Dense epilogue reads h1 from SGPRs; Wd/bd preloaded into VGPRs at
//     startup so the tail has no cold loads.
//
// Layout recap: lane 16r+3u+p owns gate column p*20+(5r+u) (p=0:z 1:r 2:h~);
// gate hops are two chained v_mov_dpp row_shr:1 (never cross a 16-lane row);
// home lane of unit j = 16*(j/5) + 3*(j%5) + 2 holds h[j].

#define BB 2048
#define TT 128
#define HH 20
#define LL 15
#define H3 60

__device__ __forceinline__ float bclane(float v, int k) {
    return __int_as_float(__builtin_amdgcn_readlane(__float_as_int(v), k));
}
__device__ __forceinline__ float rdhome(float v, int j) {
    // home lane of unit j (compile-time constant under full unroll)
    const int ln = ((j / 5) << 4) + (j % 5) * 3 + 2;
    return __int_as_float(__builtin_amdgcn_readlane(__float_as_int(v), ln));
}
__device__ __forceinline__ float dpp_rshr1(float v) {
    // v_mov_b32_dpp row_shr:1 — lane i <- lane i-1 within its 16-lane row
    return __int_as_float(__builtin_amdgcn_update_dpp(
        0, __float_as_int(v), 0x111, 0xF, 0xF, true));
}
__device__ __forceinline__ float fast_rcp(float x) { return __builtin_amdgcn_rcpf(x); }
__device__ __forceinline__ float sigm(float x) { return fast_rcp(1.f + __expf(-x)); }
__device__ __forceinline__ float tanh_f(float x) { return 1.f - 2.f * fast_rcp(1.f + __expf(2.f * x)); }
#define PIN(v) asm volatile("" : "+v"(v))

extern "C" __global__ __launch_bounds__(256)
__attribute__((amdgpu_waves_per_eu(2, 2)))
void gru2_kernel(const int* __restrict__ x, const float* __restrict__ W0,
                 const float* __restrict__ U0, const float* __restrict__ b0i,
                 const float* __restrict__ b0r, const float* __restrict__ W1,
                 const float* __restrict__ U1, const float* __restrict__ b1i,
                 const float* __restrict__ b1r, const float* __restrict__ Wd,
                 const float* __restrict__ bd, float* __restrict__ out)
{
    const int lane = threadIdx.x & 63;
    const int w = threadIdx.x >> 6;
    const int b = blockIdx.x * 4 + w;                    // batch = wave id
    const int row = lane >> 4;                           // DPP row 0..3
    const int pos = lane & 15;                           // pos in row
    const int pc  = (pos < 15) ? pos : 14;               // lane 16r+15 dups pos 14
    const int u   = pc / 3;                              // unit-in-row 0..4
    const int p3  = pc % 3;                              // 0:z 1:r 2:h~
    const int col = p3 * 20 + (row * 5 + u);             // owned gate column

    // ---- weight columns (scalar, one VGPR per k) ----
    float u0c[HH], w1c[HH], u1c[HH];
#pragma unroll
    for (int k = 0; k < HH; ++k) {
        u0c[k] = U0[k * H3 + col];
        w1c[k] = W1[k * H3 + col];
        u1c[k] = U1[k * H3 + col];
    }
#pragma unroll
    for (int k = 0; k < HH; ++k) { PIN(u0c[k]); PIN(w1c[k]); PIN(u1c[k]); }
    float bi0 = b0i[col], br0 = b0r[col], bi1 = b1i[col], br1 = b1r[col];
    PIN(bi0); PIN(br0); PIN(bi1); PIN(br1);

    // ---- dense weights preloaded (used once at the end) ----
    const int l = lane < LL ? lane : LL - 1;
    float wdc[HH];
#pragma unroll
    for (int k = 0; k < HH; ++k) wdc[k] = Wd[k * LL + l];
    float bdl = bd[l];
#pragma unroll
    for (int k = 0; k < HH; ++k) PIN(wdc[k]);
    PIN(bdl);

    // ---- tokens ----
    const int* xrow = x + b * TT;
    const int tokA = xrow[lane];
    const int tokB = xrow[64 + lane];

    float h0 = 0.f, h1 = 0.f;                            // home lanes hold state

    // ---- W0 pipeline: row t ready, row t+1 raw, token t+2 staged ----
    const int tok0 = __builtin_amdgcn_readlane(tokA, 0);
    const int tok1 = __builtin_amdgcn_readlane(tokA, 1);
    int tokn2 = __builtin_amdgcn_readlane(tokA, 2);
    float xw_cur = W0[tok0 * H3 + col] + bi0;
    float xw_nxt = W0[tok1 * H3 + col];

    float s0[HH];                                        // SGPR-resident h0
    float rec0, xw1, rec1;                               // carried dot results

    // tail dot block: s0 (=h0_t) feeds rec0/xw1; h1 (=h1_{t-1}) is lifted
    // lane-by-lane and consumed immediately by the rec1 chain (short SGPR
    // live ranges). Two interleaved fmac chains per dot.
#define DOTS()                                                                \
    {                                                                         \
        float a0 = br0, e0 = 0.f;                                             \
        float a1 = bi1, e1 = 0.f;                                             \
        float a2 = br1, e2 = 0.f;                                             \
        _Pragma("unroll")                                                     \
        for (int k = 0; k < HH / 2; ++k) {                                    \
            a0 = fmaf(s0[2 * k],     u0c[2 * k],     a0);                     \
            e0 = fmaf(s0[2 * k + 1], u0c[2 * k + 1], e0);                     \
            a1 = fmaf(s0[2 * k],     w1c[2 * k],     a1);                     \
            e1 = fmaf(s0[2 * k + 1], w1c[2 * k + 1], e1);                     \
        }                                                                     \
        _Pragma("unroll")                                                     \
        for (int k = 0; k < HH / 2; ++k) {                                    \
            const float g0 = rdhome(h1, 2 * k);                               \
            const float g1 = rdhome(h1, 2 * k + 1);                           \
            a2 = fmaf(g0, u1c[2 * k],     a2);                                \
            e2 = fmaf(g1, u1c[2 * k + 1], e2);                                \
        }                                                                     \
        rec0 = a0 + e0; xw1 = a1 + e1; rec1 = a2 + e2;                        \
    }

    // ---- prologue: L0 for t=0 (h0_{-1}=0 -> rec0 = br0), then dots for i=1 ----
    {
        const float pf = W0[tokn2 * H3 + col];
        const int tokn3 = __builtin_amdgcn_readlane(tokA, 3);
        const float sg0 = sigm(xw_cur + br0);            // z on p=0, r on p=1
        const float rv0 = dpp_rshr1(sg0);                // home <- r_j
        const float zv0 = dpp_rshr1(rv0);                // home <- z_j
        const float hh0 = tanh_f(xw_cur + rv0 * br0);
        h0 = fmaf(zv0, h0 - hh0, hh0);
#pragma unroll
        for (int k = 0; k < HH; ++k) s0[k] = rdhome(h0, k);
        xw_cur = xw_nxt + bi0; xw_nxt = pf; tokn2 = tokn3;
        DOTS();                                          // rec0/xw1/rec1 for i=1
    }

    // ---- main loop: i = 1..127, L0(t=i) + L1(t=i-1); gates first, dots in tail
#pragma unroll 2
    for (int i = 1; i < TT; ++i) {
        const int t3 = (i + 3 < TT) ? (i + 3) : (TT - 1);
        const float pf = W0[tokn2 * H3 + col];
        const int tokn3 = __builtin_amdgcn_readlane(t3 < 64 ? tokA : tokB, t3 & 63);

        // ---- L0 gates (t=i): rec0 carried, chain starts immediately ----
        const float sg0 = sigm(xw_cur + rec0);
        const float rv0 = dpp_rshr1(sg0);
        const float zv0 = dpp_rshr1(rv0);
        const float hh0 = tanh_f(xw_cur + rv0 * rec0);
        h0 = fmaf(zv0, h0 - hh0, hh0);
#pragma unroll
        for (int k = 0; k < HH; ++k) s0[k] = rdhome(h0, k);   // h0 -> SGPRs

        // ---- L1 gates (t=i-1): independent of L0 above ----
        const float sg1 = sigm(xw1 + rec1);
        const float rv1 = dpp_rshr1(sg1);
        const float zv1 = dpp_rshr1(rv1);
        const float hh1 = tanh_f(xw1 + rv1 * rec1);
        h1 = fmaf(zv1, h1 - hh1, hh1);

        // rotate W0 pipeline
        xw_cur = xw_nxt + bi0; xw_nxt = pf; tokn2 = tokn3;

        // ---- tail dots for i+1 (h1 lifted inside; at i=127 xw1/rec1 feed
        //      the epilogue; rec0 is one wasted dot) ----
        DOTS();
    }

    // ---- epilogue: L1 for t=127 (xw1/rec1 from the last tail) ----
    float s1h[HH];
    {
        const float sg1 = sigm(xw1 + rec1);
        const float rv1 = dpp_rshr1(sg1);
        const float zv1 = dpp_rshr1(rv1);
        const float hh1 = tanh_f(xw1 + rv1 * rec1);
        h1 = fmaf(zv1, h1 - hh1, hh1);
#pragma unroll
        for (int k = 0; k < HH; ++k) s1h[k] = rdhome(h1, k);  // final h1
    }

    // ---- dense (h1 @ Wd + bd) + softmax, lanes 0..14 ----
    float acc = bdl;
#pragma unroll
    for (int k = 0; k < HH; ++k)
        acc = fmaf(s1h[k], wdc[k], acc);                 // SGPR x VGPR fmac

    float m = acc;
#pragma unroll
    for (int i = 0; i < LL; ++i) m = fmaxf(m, bclane(acc, i));
    const float e = __expf(acc - m);
    float s = 0.f;
#pragma unroll
    for (int i = 0; i < LL; ++i) s += bclane(e, i);
    const float pr = e * fast_rcp(s);

    if (lane < LL) out[b * LL + lane] = pr;
}

extern "C" void kernel_launch(void* const* d_in, const int* in_sizes, int n_in,
                              void* d_out, int out_size, void* d_ws, size_t ws_size,
                              hipStream_t stream) {
    const int*   x   = (const int*)  d_in[0];
    const float* W0  = (const float*)d_in[1];
    const float* U0  = (const float*)d_in[2];
    const float* b0i = (const float*)d_in[3];
    const float* b0r = (const float*)d_in[4];
    const float* W1  = (const float*)d_in[5];
    const float* U1  = (const float*)d_in[6];
    const float* b1i = (const float*)d_in[7];
    const float* b1r = (const float*)d_in[8];
    const float* Wd  = (const float*)d_in[9];
    const float* bd  = (const float*)d_in[10];
    // d_in[11] = drop_rate (identity), unused
    float* out = (float*)d_out;

    // 1 batch/wave, 4 waves/block -> 512 blocks = 2 blocks/CU = 2 waves/SIMD.
    dim3 grid(BB / 4), block(256);
    hipLaunchKernelGGL(gru2_kernel, grid, block, 0, stream,
                       x, W0, U0, b0i, b0r, W1, U1, b1i, b1r, Wd, bd, out);
}

// Round 4
// 121.202 us; speedup vs baseline: 1.1760x; 1.1760x over previous
//
#include <hip/hip_runtime.h>

// CharGRU2: 2-layer GRU (reset_after=true) + dense + softmax, fp32.
// B=2048, T=128, V=256, H=20, L=15.
//
// Round 16 = R13 base (best: 58.5us dispatch; LDS h-broadcast + pk_fma dots
// + tail-rotated rec0/xw1; the R15 readlane experiment regressed 29% and is
// reverted) + three cuts:
//
//  1. EXP2 PRE-SCALING: -log2e folded into z/r weight columns, -2log2e into
//     h~ columns (U0/W1/U1 + all biases at init; W0 gets it via fma in the
//     pipeline rotation). sigmoid(x) = rcp(1+exp2(-x*log2e)) and
//     tanh(x) = 2*rcp(1+exp2(-2x*log2e)) - 1 become the SAME
//     exp2/add/rcp stream on every lane with zero pre-multiplies:
//     -4 v_mul/iter and -16cy of trans-chain latency.
//  2. PARALLEL DPP HOPS: zv = row_shr:2(t) directly (was chained through
//     rv = row_shr:1) — the two gate hops are now independent.
//  3. rec1 DOT MOVED between the L0 and L1 gate blocks: R13 consumed the c1
//     ds_read ~10 insts after issue (~100cy exposed LDS latency per iter).
//     Now c1 (read at end of iter i-1) is consumed after tail dots + loop
//     top + the whole L0 gate block (~150cy gap, hidden), and the rec1
//     fma chain hides under L0's trans latency before L1 consumes it.
//
// Layout recap: lane 16r+3u+p owns gate column p*20+(5r+u) (p=0:z 1:r 2:h~);
// home lane of unit j = 16*(j/5)+3*(j%5)+2; lane 16r+15 dups pos 14 and is
// excluded from LDS writes. Gate hops never cross a 16-lane DPP row.

#define BB 2048
#define TT 128
#define HH 20
#define LL 15
#define H3 60

typedef float v2f __attribute__((ext_vector_type(2)));

#if __has_builtin(__builtin_amdgcn_exp2f)
#define EXP2(x) __builtin_amdgcn_exp2f(x)
#else
#define EXP2(x) exp2f(x)
#endif

__device__ __forceinline__ float bclane(float v, int k) {
    return __int_as_float(__builtin_amdgcn_readlane(__float_as_int(v), k));
}
__device__ __forceinline__ float dpp_rshr1(float v) {
    // v_mov_b32_dpp row_shr:1 — lane i <- lane i-1 within its 16-lane row
    return __int_as_float(__builtin_amdgcn_update_dpp(
        0, __float_as_int(v), 0x111, 0xF, 0xF, true));
}
__device__ __forceinline__ float dpp_rshr2(float v) {
    // v_mov_b32_dpp row_shr:2 — lane i <- lane i-2 within its 16-lane row
    return __int_as_float(__builtin_amdgcn_update_dpp(
        0, __float_as_int(v), 0x112, 0xF, 0xF, true));
}
__device__ __forceinline__ float fast_rcp(float x) { return __builtin_amdgcn_rcpf(x); }
#define PIN(v) asm volatile("" : "+v"(v))
#define LDSFENCE() asm volatile("" ::: "memory")

extern "C" __global__ __launch_bounds__(256)
__attribute__((amdgpu_waves_per_eu(2, 2)))
void gru2_kernel(const int* __restrict__ x, const float* __restrict__ W0,
                 const float* __restrict__ U0, const float* __restrict__ b0i,
                 const float* __restrict__ b0r, const float* __restrict__ W1,
                 const float* __restrict__ U1, const float* __restrict__ b1i,
                 const float* __restrict__ b1r, const float* __restrict__ Wd,
                 const float* __restrict__ bd, float* __restrict__ out)
{
    const int lane = threadIdx.x & 63;
    const int w = threadIdx.x >> 6;
    const int b = blockIdx.x * 4 + w;                    // batch = wave id
    const int row = lane >> 4;                           // DPP row 0..3
    const int pos = lane & 15;                           // pos in row
    const int pc  = (pos < 15) ? pos : 14;               // lane 16r+15 dups pos 14
    const int u   = pc / 3;                              // unit-in-row 0..4
    const int p3  = pc % 3;                              // 0:z 1:r 2:h~
    const int j   = row * 5 + u;                         // unit 0..19
    const bool home = (pos < 15) && (p3 == 2);           // 20 h-home lanes
    const int col = p3 * 20 + j;                         // owned gate column

    // exp2 gate scale: z/r columns get -log2e, h~ columns -2log2e, so
    // sigmoid = rcp(1+exp2(y)) and tanh = 2*rcp(1+exp2(y))-1 directly.
    const float gsc = (p3 == 2) ? -2.8853900817779268f : -1.4426950408889634f;

    // per-wave LDS staging of h0/h1 (wave-uniform broadcast reads)
    __shared__ __align__(16) float hbuf[4][2][24];
    float* h0buf = &hbuf[w][0][0];
    float* h1buf = &hbuf[w][1][0];
    const float4* h0q = (const float4*)h0buf;
    const float4* h1q = (const float4*)h1buf;
    if (home) { h0buf[j] = 0.f; h1buf[j] = 0.f; }
    LDSFENCE();

    // ---- weight columns (k-pair packed, pre-scaled) into VGPRs, pinned ----
    v2f u0p[10], w1p[10], u1p[10];
#pragma unroll
    for (int q = 0; q < 10; ++q) {
        const int k0 = (2 * q) * H3, k1 = (2 * q + 1) * H3;
        u0p[q] = v2f{U0[k0 + col] * gsc, U0[k1 + col] * gsc};
        w1p[q] = v2f{W1[k0 + col] * gsc, W1[k1 + col] * gsc};
        u1p[q] = v2f{U1[k0 + col] * gsc, U1[k1 + col] * gsc};
    }
#pragma unroll
    for (int q = 0; q < 10; ++q) { PIN(u0p[q]); PIN(w1p[q]); PIN(u1p[q]); }
    float bi0 = b0i[col] * gsc, br0 = b0r[col] * gsc;
    float bi1 = b1i[col] * gsc, br1 = b1r[col] * gsc;
    PIN(bi0); PIN(br0); PIN(bi1); PIN(br1);

    // ---- tokens ----
    const int* xrow = x + b * TT;
    const int tokA = xrow[lane];
    const int tokB = xrow[64 + lane];

    float h0 = 0.f, h1 = 0.f;                            // home lanes hold state

    // ---- W0 pipeline: row t ready(scaled), row t+1 raw, token t+2 staged ----
    const int tok0 = __builtin_amdgcn_readlane(tokA, 0);
    const int tok1 = __builtin_amdgcn_readlane(tokA, 1);
    int tokn2 = __builtin_amdgcn_readlane(tokA, 2);
    float xw_cur = fmaf(W0[tok0 * H3 + col], gsc, bi0);
    float xw_nxt = W0[tok1 * H3 + col];                  // raw

    float4 c0[5], c1[5];                                 // register-staged h quads
    float rec0, xw1, rec1;                               // carried dot results

    // dots from c0 (=h0_t): rec0 (U0) + xw1 (W1), two 5-deep pk chains each
#define DOT01()                                                               \
    {                                                                         \
        v2f a0a = v2f{br0, 0.f}, a0b = v2f{0.f, 0.f};                         \
        v2f a1a = v2f{bi1, 0.f}, a1b = v2f{0.f, 0.f};                         \
        _Pragma("unroll")                                                     \
        for (int q = 0; q < 5; ++q) {                                         \
            const v2f hA = v2f{c0[q].x, c0[q].y}, hB = v2f{c0[q].z, c0[q].w}; \
            a0a = __builtin_elementwise_fma(hA, u0p[2 * q], a0a);             \
            a0b = __builtin_elementwise_fma(hB, u0p[2 * q + 1], a0b);         \
            a1a = __builtin_elementwise_fma(hA, w1p[2 * q], a1a);             \
            a1b = __builtin_elementwise_fma(hB, w1p[2 * q + 1], a1b);         \
        }                                                                     \
        { const v2f t = a0a + a0b; rec0 = t.x + t.y; }                        \
        { const v2f t = a1a + a1b; xw1  = t.x + t.y; }                        \
    }
    // dot from c1 (=h1_{t-1}): rec1 (U1)
#define DOT2()                                                                \
    {                                                                         \
        v2f a2a = v2f{br1, 0.f}, a2b = v2f{0.f, 0.f};                         \
        _Pragma("unroll")                                                     \
        for (int q = 0; q < 5; ++q) {                                         \
            const v2f gA = v2f{c1[q].x, c1[q].y}, gB = v2f{c1[q].z, c1[q].w}; \
            a2a = __builtin_elementwise_fma(gA, u1p[2 * q], a2a);             \
            a2b = __builtin_elementwise_fma(gB, u1p[2 * q + 1], a2b);         \
        }                                                                     \
        { const v2f t = a2a + a2b; rec1 = t.x + t.y; }                        \
    }
    // gate block: e/t stream serves z,r (sigmoid) AND h~ (tanh) lanes
#define GATES(XW, REC, H)                                                     \
    {                                                                         \
        const float e  = EXP2((XW) + (REC));                                  \
        const float t  = fast_rcp(1.f + e);                                   \
        const float rv = dpp_rshr1(t);                                        \
        const float zv = dpp_rshr2(t);                                        \
        const float eh = EXP2(fmaf(rv, (REC), (XW)));                         \
        const float th = fast_rcp(1.f + eh);                                  \
        const float hh = fmaf(2.f, th, -1.f);                                 \
        H = fmaf(zv, (H) - hh, hh);                                           \
    }

    // ---- prologue: L0 for t=0 (h0_{-1}=0 -> rec0 = br0); c1 = zeros ----
    {
        const float pf = W0[tokn2 * H3 + col];
        const int tokn3 = __builtin_amdgcn_readlane(tokA, 3);
        GATES(xw_cur, br0, h0);
        if (home) h0buf[j] = h0;
        LDSFENCE();
#pragma unroll
        for (int q = 0; q < 5; ++q) { c0[q] = h0q[q]; c1[q] = h1q[q]; }
        xw_cur = fmaf(xw_nxt, gsc, bi0); xw_nxt = pf; tokn2 = tokn3;
        DOT01();                                         // rec0/xw1 for i=1
    }

    // ---- main loop: i = 1..127 — L0 gates / rec1 dot / L1 gates / tail dots
#pragma unroll 2
    for (int i = 1; i < TT; ++i) {
        const int t3 = (i + 3 < TT) ? (i + 3) : (TT - 1);
        const float pf = W0[tokn2 * H3 + col];
        const int tokn3 = __builtin_amdgcn_readlane(t3 < 64 ? tokA : tokB, t3 & 63);

        // ---- L0 gates (t=i): rec0/xw_cur carried, chain starts now ----
        GATES(xw_cur, rec0, h0);
        if (home) h0buf[j] = h0;
        LDSFENCE();
#pragma unroll
        for (int q = 0; q < 5; ++q) c0[q] = h0q[q];      // next h0 quads

        // ---- rec1 dot: c1 read one full iteration ago (latency hidden);
        //      chain hides under L0's trans latency before L1 needs it ----
        DOT2();

        // ---- L1 gates (t=i-1) ----
        GATES(xw1, rec1, h1);
        if (home) h1buf[j] = h1;
        LDSFENCE();
#pragma unroll
        for (int q = 0; q < 5; ++q) c1[q] = h1q[q];      // next h1 quads

        // rotate W0 pipeline (scale applied here: fma, not add)
        xw_cur = fmaf(xw_nxt, gsc, bi0); xw_nxt = pf; tokn2 = tokn3;

        // ---- tail dots for i+1: consume c0 (gap = rec1 dot + L1 gates) ----
        DOT01();
    }

    // ---- epilogue: L1 for t=127 (xw1 carried; rec1 from final c1) ----
    {
        DOT2();
        GATES(xw1, rec1, h1);
        if (home) h1buf[j] = h1;                         // final h1
        LDSFENCE();
    }

    // ---- dense (h1 @ Wd + bd) + softmax, lanes 0..14 ----
    const int l = lane < LL ? lane : LL - 1;
    float acc = bd[l];
#pragma unroll
    for (int k = 0; k < HH; ++k)
        acc = fmaf(h1buf[k], Wd[k * LL + l], acc);       // LDS broadcast reads

    float m = acc;
#pragma unroll
    for (int i = 0; i < LL; ++i) m = fmaxf(m, bclane(acc, i));
    const float e = __expf(acc - m);
    float s = 0.f;
#pragma unroll
    for (int i = 0; i < LL; ++i) s += bclane(e, i);
    const float pr = e * fast_rcp(s);

    if (lane < LL) out[b * LL + lane] = pr;
}

extern "C" void kernel_launch(void* const* d_in, const int* in_sizes, int n_in,
                              void* d_out, int out_size, void* d_ws, size_t ws_size,
                              hipStream_t stream) {
    const int*   x   = (const int*)  d_in[0];
    const float* W0  = (const float*)d_in[1];
    const float* U0  = (const float*)d_in[2];
    const float* b0i = (const float*)d_in[3];
    const float* b0r = (const float*)d_in[4];
    const float* W1  = (const float*)d_in[5];
    const float* U1  = (const float*)d_in[6];
    const float* b1i = (const float*)d_in[7];
    const float* b1r = (const float*)d_in[8];
    const float* Wd  = (const float*)d_in[9];
    const float* bd  = (const float*)d_in[10];
    // d_in[11] = drop_rate (identity), unused
    float* out = (float*)d_out;

    // 1 batch/wave, 4 waves/block -> 512 blocks = 2 blocks/CU = 2 waves/SIMD.
    dim3 grid(BB / 4), block(256);
    hipLaunchKernelGGL(gru2_kernel, grid, block, 0, stream,
                       x, W0, U0, b0i, b0r, W1, U1, b1i, b1r, Wd, bd, out);
}